// Round 1
// baseline (177.915 us; speedup 1.0000x reference)
//
#include <hip/hip_runtime.h>
#include <math.h>

#define BB 8
#define NN 8192
#define MM 4096
#define HH 128
#define WW 128

#define WAVES 8
#define PTS 64                 // points per block
#define SLICE (NN / WAVES)     // 1024 candidates per wave

// ---------------------------------------------------------------------------
// Kernel 1: per-batch mean of yc_on  (fill value for OOB bilinear)
// ---------------------------------------------------------------------------
__global__ void mean_kernel(const float* __restrict__ yc_on,
                            float* __restrict__ means) {
    int b = blockIdx.x;
    const float* p = yc_on + b * (HH * WW);
    float s = 0.f;
    for (int i = threadIdx.x; i < HH * WW; i += blockDim.x) s += p[i];
    // wave64 reduce
    for (int off = 32; off > 0; off >>= 1) s += __shfl_down(s, off, 64);
    __shared__ float partial[4];
    int wave = threadIdx.x >> 6;
    if ((threadIdx.x & 63) == 0) partial[wave] = s;
    __syncthreads();
    if (threadIdx.x == 0) {
        float t = 0.f;
        int nw = blockDim.x >> 6;
        for (int i = 0; i < nw; ++i) t += partial[i];
        means[b] = t * (1.0f / (HH * WW));
    }
}

// ---------------------------------------------------------------------------
// Kernel 2: brute-force NN (slice-split across 8 waves) + bilinear + mix
// grid = B * (M/PTS) = 512 blocks, block = 512 threads (8 waves)
// ---------------------------------------------------------------------------
__global__ __launch_bounds__(WAVES * 64)
void nn_kernel(const float* __restrict__ xc_off,   // (B,N,2)
               const float* __restrict__ yc_off,   // (B,N)
               const float* __restrict__ yc_on,    // (B,H,W)
               const float* __restrict__ xt,       // (B,M,2)
               const float* __restrict__ means,    // (B)
               const float* __restrict__ logit_p,  // (1)
               float* __restrict__ out)            // (B,M)
{
    const int blocksPerBatch = MM / PTS;           // 64
    const int b     = blockIdx.x / blocksPerBatch;
    const int pbase = (blockIdx.x % blocksPerBatch) * PTS;
    const int wave  = threadIdx.x >> 6;
    const int lane  = threadIdx.x & 63;
    const int m     = pbase + lane;

    const float2 pt = ((const float2*)xt)[b * MM + m];   // per-lane 8B load
    const float px = pt.x, py = pt.y;

    const float2* __restrict__ cxy = ((const float2*)xc_off) + (size_t)b * NN;
    const float*  __restrict__ cv  = yc_off + (size_t)b * NN;

    float best  = 3.4e38f;
    float bestv = 0.f;

    const int j0 = wave * SLICE;
    for (int t = 0; t < SLICE; t += 8) {
#pragma unroll
        for (int u = 0; u < 8; ++u) {
            const int j = j0 + t + u;         // wave-uniform -> s_load path
            const float2 c = cxy[j];
            const float  v = cv[j];
            const float dx = px - c.x;
            const float dy = py - c.y;
            const float d2 = fmaf(dx, dx, dy * dy);
            const bool lt = d2 < best;        // strict < keeps first index
            best  = lt ? d2 : best;
            bestv = lt ? v  : bestv;
        }
    }

    __shared__ float sd2[WAVES][PTS];
    __shared__ float sv [WAVES][PTS];
    sd2[wave][lane] = best;
    sv [wave][lane] = bestv;
    __syncthreads();

    if (threadIdx.x < PTS) {
        // combine slices in ascending order (ties -> lowest index, like argmin)
        float bd = sd2[0][lane];
        float bv = sv [0][lane];
#pragma unroll
        for (int wv = 1; wv < WAVES; ++wv) {
            const float d  = sd2[wv][lane];
            const float vv = sv [wv][lane];
            if (d < bd) { bd = d; bv = vv; }
        }

        // ---- bilinear on the regular linspace grid ----
        const float* __restrict__ vals = yc_on + (size_t)b * HH * WW;
        const float x = px, y = py;
        int ix = (int)floorf(x * 127.0f);
        int iy = (int)floorf(y * 127.0f);
        ix = ix < 0 ? 0 : (ix > 126 ? 126 : ix);
        iy = iy < 0 ? 0 : (iy > 126 ? 126 : iy);
        const float x0 = (float)ix * (1.0f / 127.0f);
        const float x1 = (float)(ix + 1) * (1.0f / 127.0f);
        const float y0 = (float)iy * (1.0f / 127.0f);
        const float y1 = (float)(iy + 1) * (1.0f / 127.0f);
        const float wx = (x - x0) / (x1 - x0);
        const float wy = (y - y0) / (y1 - y0);
        const float v00 = vals[ix * WW + iy];
        const float v01 = vals[ix * WW + iy + 1];
        const float v10 = vals[(ix + 1) * WW + iy];
        const float v11 = vals[(ix + 1) * WW + iy + 1];
        float vi = (1.f - wx) * (1.f - wy) * v00
                 + (1.f - wx) * wy         * v01
                 + wx         * (1.f - wy) * v10
                 + wx         * wy         * v11;
        const bool oob = (x < 0.f) || (x > 1.f) || (y < 0.f) || (y > 1.f);
        const float yon = oob ? means[b] : vi;

        const float l   = logit_p[0];
        const float mix = 1.f / (1.f + expf(-l));
        out[(size_t)b * MM + m] = mix * bv + (1.f - mix) * yon;
    }
}

// ---------------------------------------------------------------------------
extern "C" void kernel_launch(void* const* d_in, const int* in_sizes, int n_in,
                              void* d_out, int out_size, void* d_ws, size_t ws_size,
                              hipStream_t stream) {
    const float* xc_off = (const float*)d_in[0];   // (B,N,2)
    const float* yc_off = (const float*)d_in[1];   // (B,N)
    // d_in[2] = xc_on_grid (B,H,W,2) -- regular linspace grid, not needed
    const float* yc_on  = (const float*)d_in[3];   // (B,H,W)
    const float* xt     = (const float*)d_in[4];   // (B,M,2)
    const float* logit  = (const float*)d_in[5];   // scalar
    float* out = (float*)d_out;
    float* means = (float*)d_ws;                   // B floats of scratch

    mean_kernel<<<BB, 256, 0, stream>>>(yc_on, means);
    nn_kernel<<<BB * (MM / PTS), WAVES * 64, 0, stream>>>(
        xc_off, yc_off, yc_on, xt, means, logit, out);
}

// Round 3
// 130.173 us; speedup vs baseline: 1.3668x; 1.3668x over previous
//
#include <hip/hip_runtime.h>
#include <math.h>

#define BB 8
#define NN 8192
#define MM 4096
#define HH 128
#define WW 128

#define G    32
#define GG   (G * G)
#define CELL (1.0f / G)

// ws layout:
//   [0, 32)                      means (8 floats)
//   [256, 256 + 8*1025*4)        starts (B x (GG+1) ints)
//   [33056, +8*8192*16)          cellData (B x N float4: x, y, val, idx-bits)
#define WS_STARTS_OFF   256
#define WS_CELLS_OFF    33056
#define WS_NEEDED       (WS_CELLS_OFF + (size_t)BB * NN * 16)

// ---------------------------------------------------------------------------
// Kernel 1: per-batch mean of yc_on (fill value for OOB bilinear) — validated
// bit-exact in R1.
// ---------------------------------------------------------------------------
__global__ void mean_kernel(const float* __restrict__ yc_on,
                            float* __restrict__ means) {
    int b = blockIdx.x;
    const float* p = yc_on + b * (HH * WW);
    float s = 0.f;
    for (int i = threadIdx.x; i < HH * WW; i += blockDim.x) s += p[i];
    for (int off = 32; off > 0; off >>= 1) s += __shfl_down(s, off, 64);
    __shared__ float partial[4];
    int wave = threadIdx.x >> 6;
    if ((threadIdx.x & 63) == 0) partial[wave] = s;
    __syncthreads();
    if (threadIdx.x == 0) {
        float t = 0.f;
        int nw = blockDim.x >> 6;
        for (int i = 0; i < nw; ++i) t += partial[i];
        means[b] = t * (1.0f / (HH * WW));
    }
}

// ---------------------------------------------------------------------------
// Kernel 2: bin candidates into a G x G uniform grid (one block per batch).
// counts -> exclusive scan (wave shfl scan + wave-offset scan) -> scatter.
// ---------------------------------------------------------------------------
__global__ __launch_bounds__(1024)
void bin_kernel(const float* __restrict__ xc_off,   // (B,N,2)
                const float* __restrict__ yc_off,   // (B,N)
                int* __restrict__ starts,           // (B, GG+1)
                float4* __restrict__ cellData)      // (B, N)
{
    const int b   = blockIdx.x;
    const int tid = threadIdx.x;
    __shared__ int cnt[GG];
    __shared__ int wsum[16];
    cnt[tid] = 0;
    __syncthreads();

    const float2* __restrict__ cxy = ((const float2*)xc_off) + (size_t)b * NN;
    float2 pts[NN / 1024];
    int    cells[NN / 1024];
#pragma unroll
    for (int k = 0; k < NN / 1024; ++k) {
        float2 c = cxy[tid + k * 1024];
        int gx = (int)(c.x * (float)G); gx = gx < 0 ? 0 : (gx > G - 1 ? G - 1 : gx);
        int gy = (int)(c.y * (float)G); gy = gy < 0 ? 0 : (gy > G - 1 ? G - 1 : gy);
        pts[k]   = c;
        cells[k] = gx * G + gy;
        atomicAdd(&cnt[cells[k]], 1);
    }
    __syncthreads();

    const int orig = cnt[tid];
    int x = orig;
    const int lane = tid & 63, wid = tid >> 6;
    for (int off = 1; off < 64; off <<= 1) {
        int y = __shfl_up(x, off, 64);
        if (lane >= off) x += y;
    }
    if (lane == 63) wsum[wid] = x;
    __syncthreads();
    if (tid < 16) {
        int w = wsum[tid];
        for (int off = 1; off < 16; off <<= 1) {
            int y = __shfl_up(w, off, 16);
            if (tid >= off) w += y;
        }
        wsum[tid] = w;
    }
    __syncthreads();
    const int incl = x + (wid ? wsum[wid - 1] : 0);
    const int excl = incl - orig;
    starts[b * (GG + 1) + tid] = excl;
    if (tid == GG - 1) starts[b * (GG + 1) + GG] = incl;   // == N
    __syncthreads();
    cnt[tid] = excl;   // running cursors for scatter
    __syncthreads();

    const float* __restrict__ cv = yc_off + (size_t)b * NN;
#pragma unroll
    for (int k = 0; k < NN / 1024; ++k) {
        const int i = tid + k * 1024;
        const float v = cv[i];
        const int pos = atomicAdd(&cnt[cells[k]], 1);
        cellData[(size_t)b * NN + pos] =
            make_float4(pts[k].x, pts[k].y, v, __int_as_float(i));
    }
}

// ---------------------------------------------------------------------------
// Bilinear + mix epilogue, shared by both query paths.
// ---------------------------------------------------------------------------
__device__ __forceinline__ float epilogue(const float* __restrict__ yc_on,
                                          const float* __restrict__ means,
                                          const float* __restrict__ logit_p,
                                          int b, float px, float py, float bv) {
    const float* __restrict__ vals = yc_on + (size_t)b * HH * WW;
    const float x = px, y = py;
    int ix = (int)floorf(x * 127.0f);
    int iy = (int)floorf(y * 127.0f);
    ix = ix < 0 ? 0 : (ix > 126 ? 126 : ix);
    iy = iy < 0 ? 0 : (iy > 126 ? 126 : iy);
    const float x0 = (float)ix * (1.0f / 127.0f);
    const float x1 = (float)(ix + 1) * (1.0f / 127.0f);
    const float y0 = (float)iy * (1.0f / 127.0f);
    const float y1 = (float)(iy + 1) * (1.0f / 127.0f);
    const float wx = (x - x0) / (x1 - x0);
    const float wy = (y - y0) / (y1 - y0);
    const float v00 = vals[ix * WW + iy];
    const float v01 = vals[ix * WW + iy + 1];
    const float v10 = vals[(ix + 1) * WW + iy];
    const float v11 = vals[(ix + 1) * WW + iy + 1];
    float vi = (1.f - wx) * (1.f - wy) * v00
             + (1.f - wx) * wy         * v01
             + wx         * (1.f - wy) * v10
             + wx         * wy         * v11;
    const bool oob = (x < 0.f) || (x > 1.f) || (y < 0.f) || (y > 1.f);
    const float yon = oob ? means[b] : vi;
    const float l   = logit_p[0];
    const float mix = 1.f / (1.f + expf(-l));
    return mix * bv + (1.f - mix) * yon;
}

// ---------------------------------------------------------------------------
// Kernel 3: grid NN query (2 lanes per point, alternate cell-rows) + epilogue.
// Lexicographic (d2, idx) == argmin first-index semantics, order-independent.
// ---------------------------------------------------------------------------
__global__ __launch_bounds__(256)
void query_kernel(const int* __restrict__ starts,
                  const float4* __restrict__ cellData,
                  const float* __restrict__ yc_on,    // (B,H,W)
                  const float* __restrict__ xt,       // (B,M,2)
                  const float* __restrict__ means,    // (B)
                  const float* __restrict__ logit_p,  // (1)
                  float* __restrict__ out)            // (B,M)
{
    const int gid = blockIdx.x * blockDim.x + threadIdx.x;
    const int pid = gid >> 1;        // point id in [0, B*M)
    const int sub = gid & 1;         // which half of the lane pair
    const int b = pid / MM;
    const int m = pid % MM;

    const float2 pt = ((const float2*)xt)[pid];
    const float px = pt.x, py = pt.y;

    int cx = (int)(px * (float)G); cx = cx < 0 ? 0 : (cx > G - 1 ? G - 1 : cx);
    int cy = (int)(py * (float)G); cy = cy < 0 ? 0 : (cy > G - 1 ? G - 1 : cy);

    const int*    __restrict__ st = starts + b * (GG + 1);
    const float4* __restrict__ cd = cellData + (size_t)b * NN;

    float bd0 = 3.4e38f, bd1 = 3.4e38f;
    float bv0 = 0.f,     bv1 = 0.f;
    int   bi0 = 0x7fffffff, bi1 = 0x7fffffff;

    for (int r = 1; r <= G; ++r) {
        const int gx0 = (cx - r < 0) ? 0 : cx - r;
        const int gx1 = (cx + r > G - 1) ? G - 1 : cx + r;
        const int gy0 = (cy - r < 0) ? 0 : cy - r;
        const int gy1 = (cy + r > G - 1) ? G - 1 : cy + r;

        // this lane takes every other cell-row (rows are gy-contiguous ranges)
        for (int gx = gx0 + sub; gx <= gx1; gx += 2) {
            const int lo = st[gx * G + gy0];
            const int hi = st[gx * G + gy1 + 1];
            int j = lo;
            for (; j + 1 < hi; j += 2) {
                const float4 c0 = cd[j];
                const float4 c1 = cd[j + 1];
                const float dx0 = px - c0.x, dy0 = py - c0.y;
                const float dx1 = px - c1.x, dy1 = py - c1.y;
                const float d20 = fmaf(dx0, dx0, dy0 * dy0);
                const float d21 = fmaf(dx1, dx1, dy1 * dy1);
                const int i0 = __float_as_int(c0.w);
                const int i1 = __float_as_int(c1.w);
                if (d20 < bd0 || (d20 == bd0 && i0 < bi0)) { bd0 = d20; bv0 = c0.z; bi0 = i0; }
                if (d21 < bd1 || (d21 == bd1 && i1 < bi1)) { bd1 = d21; bv1 = c1.z; bi1 = i1; }
            }
            if (j < hi) {
                const float4 c0 = cd[j];
                const float dx0 = px - c0.x, dy0 = py - c0.y;
                const float d20 = fmaf(dx0, dx0, dy0 * dy0);
                const int i0 = __float_as_int(c0.w);
                if (d20 < bd0 || (d20 == bd0 && i0 < bi0)) { bd0 = d20; bv0 = c0.z; bi0 = i0; }
            }
        }

        // merge dual accumulators (lexicographic -> order-independent)
        if (bd1 < bd0 || (bd1 == bd0 && bi1 < bi0)) { bd0 = bd1; bv0 = bv1; bi0 = bi1; }

        // merge across the lane pair; both lanes end with identical state
        const float od = __shfl_xor(bd0, 1, 64);
        const float ov = __shfl_xor(bv0, 1, 64);
        const int   oi = __shfl_xor(bi0, 1, 64);
        if (od < bd0 || (od == bd0 && oi < bi0)) { bd0 = od; bv0 = ov; bi0 = oi; }

        // after square r, all unseen candidates are >= r*CELL away
        const float rr = (float)r * CELL;
        if (rr * rr > bd0) break;
    }

    if (sub == 0)
        out[(size_t)b * MM + m] = epilogue(yc_on, means, logit_p, b, px, py, bv0);
}

// ---------------------------------------------------------------------------
// Fallback: R1 brute-force NN (validated absmax 0.0) — used only if ws_size
// is too small for the binned layout.
// ---------------------------------------------------------------------------
#define WAVES 8
#define PTS 64
#define SLICE (NN / WAVES)

__global__ __launch_bounds__(WAVES * 64)
void nn_kernel(const float* __restrict__ xc_off,
               const float* __restrict__ yc_off,
               const float* __restrict__ yc_on,
               const float* __restrict__ xt,
               const float* __restrict__ means,
               const float* __restrict__ logit_p,
               float* __restrict__ out)
{
    const int blocksPerBatch = MM / PTS;
    const int b     = blockIdx.x / blocksPerBatch;
    const int pbase = (blockIdx.x % blocksPerBatch) * PTS;
    const int wave  = threadIdx.x >> 6;
    const int lane  = threadIdx.x & 63;
    const int m     = pbase + lane;

    const float2 pt = ((const float2*)xt)[b * MM + m];
    const float px = pt.x, py = pt.y;

    const float2* __restrict__ cxy = ((const float2*)xc_off) + (size_t)b * NN;
    const float*  __restrict__ cv  = yc_off + (size_t)b * NN;

    float best = 3.4e38f, bestv = 0.f;
    const int j0 = wave * SLICE;
    for (int t = 0; t < SLICE; t += 8) {
#pragma unroll
        for (int u = 0; u < 8; ++u) {
            const int j = j0 + t + u;
            const float2 c = cxy[j];
            const float  v = cv[j];
            const float dx = px - c.x;
            const float dy = py - c.y;
            const float d2 = fmaf(dx, dx, dy * dy);
            const bool lt = d2 < best;
            best  = lt ? d2 : best;
            bestv = lt ? v  : bestv;
        }
    }

    __shared__ float sd2[WAVES][PTS];
    __shared__ float sv [WAVES][PTS];
    sd2[wave][lane] = best;
    sv [wave][lane] = bestv;
    __syncthreads();

    if (threadIdx.x < PTS) {
        float bd = sd2[0][lane];
        float bv = sv [0][lane];
#pragma unroll
        for (int wv = 1; wv < WAVES; ++wv) {
            if (sd2[wv][lane] < bd) { bd = sd2[wv][lane]; bv = sv[wv][lane]; }
        }
        out[(size_t)b * MM + m] = epilogue(yc_on, means, logit_p, b, px, py, bv);
    }
}

// ---------------------------------------------------------------------------
extern "C" void kernel_launch(void* const* d_in, const int* in_sizes, int n_in,
                              void* d_out, int out_size, void* d_ws, size_t ws_size,
                              hipStream_t stream) {
    const float* xc_off = (const float*)d_in[0];   // (B,N,2)
    const float* yc_off = (const float*)d_in[1];   // (B,N)
    // d_in[2] = xc_on_grid (regular linspace grid, not needed)
    const float* yc_on  = (const float*)d_in[3];   // (B,H,W)
    const float* xt     = (const float*)d_in[4];   // (B,M,2)
    const float* logit  = (const float*)d_in[5];   // scalar
    float* out = (float*)d_out;

    float* means = (float*)d_ws;
    mean_kernel<<<BB, 256, 0, stream>>>(yc_on, means);

    if (ws_size >= WS_NEEDED) {
        int*    starts   = (int*)((char*)d_ws + WS_STARTS_OFF);
        float4* cellData = (float4*)((char*)d_ws + WS_CELLS_OFF);
        bin_kernel<<<BB, 1024, 0, stream>>>(xc_off, yc_off, starts, cellData);
        query_kernel<<<(BB * MM * 2) / 256, 256, 0, stream>>>(
            starts, cellData, yc_on, xt, means, logit, out);
    } else {
        nn_kernel<<<BB * (MM / PTS), WAVES * 64, 0, stream>>>(
            xc_off, yc_off, yc_on, xt, means, logit, out);
    }
}

// Round 4
// 113.445 us; speedup vs baseline: 1.5683x; 1.1475x over previous
//
#include <hip/hip_runtime.h>
#include <math.h>
#include <float.h>

#define BB 8
#define NN 8192
#define MM 4096
#define HH 128
#define WW 128

#define G    32
#define GG   (G * G)
#define CELL (1.0f / G)

// ws layout (16B-aligned sections):
//   [0, 32)              means (8 floats)
//   [256, 33024)         counts->cursors (B x GG ints, reused in-place)
//   [33024, 65824)       starts (B x (GG+1) ints)
//   [65824, +1MiB)       cellData (B x N float4: x, y, val, idx-bits)
#define WS_COUNTS_OFF 256
#define WS_STARTS_OFF 33024
#define WS_CELLS_OFF  65824
#define WS_NEEDED     (WS_CELLS_OFF + (size_t)BB * NN * 16)

__device__ __forceinline__ int clampi(int v, int lo, int hi) {
    return v < lo ? lo : (v > hi ? hi : v);
}

// ---------------------------------------------------------------------------
// Kernel 1: per-batch mean of yc_on + zero the count buffer (fused to save a
// launch). Mean path validated bit-exact in R1/R3.
// ---------------------------------------------------------------------------
__global__ void mean_zero_kernel(const float* __restrict__ yc_on,
                                 float* __restrict__ means,
                                 int* __restrict__ counts) {
    int b = blockIdx.x;
    if (counts) {
        int* c = counts + b * GG;
        for (int i = threadIdx.x; i < GG; i += blockDim.x) c[i] = 0;
    }
    const float* p = yc_on + b * (HH * WW);
    float s = 0.f;
    for (int i = threadIdx.x; i < HH * WW; i += blockDim.x) s += p[i];
    for (int off = 32; off > 0; off >>= 1) s += __shfl_down(s, off, 64);
    __shared__ float partial[4];
    int wave = threadIdx.x >> 6;
    if ((threadIdx.x & 63) == 0) partial[wave] = s;
    __syncthreads();
    if (threadIdx.x == 0) {
        float t = 0.f;
        int nw = blockDim.x >> 6;
        for (int i = 0; i < nw; ++i) t += partial[i];
        means[b] = t * (1.0f / (HH * WW));
    }
}

// ---------------------------------------------------------------------------
// Kernel 2a: count candidates per cell (global atomics, 32768 threads).
// ---------------------------------------------------------------------------
__global__ __launch_bounds__(256)
void count_kernel(const float* __restrict__ xc_off,   // (B,N,2)
                  int* __restrict__ counts) {         // (B,GG)
    const int i = blockIdx.x * blockDim.x + threadIdx.x;   // 0..32767
#pragma unroll
    for (int k = 0; k < 2; ++k) {
        const int idx = i + k * 32768;      // 0 .. B*N-1
        const int b = idx >> 13;            // / NN
        const float2 c = ((const float2*)xc_off)[idx];
        const int gx = clampi((int)(c.x * (float)G), 0, G - 1);
        const int gy = clampi((int)(c.y * (float)G), 0, G - 1);
        atomicAdd(&counts[b * GG + gx * G + gy], 1);
    }
}

// ---------------------------------------------------------------------------
// Kernel 2b: per-batch exclusive scan of counts -> starts; reset cursors
// (in-place over counts; each thread reads its own slot before writing).
// Scan code validated in R3's bin_kernel.
// ---------------------------------------------------------------------------
__global__ __launch_bounds__(1024)
void scan_kernel(int* __restrict__ counts,            // (B,GG) -> cursors
                 int* __restrict__ starts) {          // (B,GG+1)
    const int b = blockIdx.x, tid = threadIdx.x;
    __shared__ int wsum[16];
    const int orig = counts[b * GG + tid];
    int x = orig;
    const int lane = tid & 63, wid = tid >> 6;
    for (int off = 1; off < 64; off <<= 1) {
        int y = __shfl_up(x, off, 64);
        if (lane >= off) x += y;
    }
    if (lane == 63) wsum[wid] = x;
    __syncthreads();
    if (tid < 16) {
        int w = wsum[tid];
        for (int off = 1; off < 16; off <<= 1) {
            int y = __shfl_up(w, off, 16);
            if (tid >= off) w += y;
        }
        wsum[tid] = w;
    }
    __syncthreads();
    const int incl = x + (wid ? wsum[wid - 1] : 0);
    const int excl = incl - orig;
    starts[b * (GG + 1) + tid] = excl;
    if (tid == GG - 1) starts[b * (GG + 1) + GG] = incl;   // == N
    counts[b * GG + tid] = excl;   // cursor for scatter
}

// ---------------------------------------------------------------------------
// Kernel 2c: scatter candidates into cell order (atomic cursors).
// Bin-internal order is nondeterministic; harmless — query uses
// order-independent lexicographic (d2, idx) min.
// ---------------------------------------------------------------------------
__global__ __launch_bounds__(256)
void scatter_kernel(const float* __restrict__ xc_off,  // (B,N,2)
                    const float* __restrict__ yc_off,  // (B,N)
                    int* __restrict__ cursors,         // (B,GG)
                    float4* __restrict__ cellData) {   // (B,N)
    const int i = blockIdx.x * blockDim.x + threadIdx.x;
#pragma unroll
    for (int k = 0; k < 2; ++k) {
        const int idx = i + k * 32768;
        const int b = idx >> 13;
        const int n = idx & (NN - 1);       // within-batch index
        const float2 c = ((const float2*)xc_off)[idx];
        const float v = yc_off[idx];
        const int gx = clampi((int)(c.x * (float)G), 0, G - 1);
        const int gy = clampi((int)(c.y * (float)G), 0, G - 1);
        const int pos = atomicAdd(&cursors[b * GG + gx * G + gy], 1);
        cellData[(size_t)b * NN + pos] = make_float4(c.x, c.y, v, __int_as_float(n));
    }
}

// ---------------------------------------------------------------------------
// Bilinear + mix epilogue (validated in R1/R3).
// ---------------------------------------------------------------------------
__device__ __forceinline__ float epilogue(const float* __restrict__ yc_on,
                                          const float* __restrict__ means,
                                          const float* __restrict__ logit_p,
                                          int b, float px, float py, float bv) {
    const float* __restrict__ vals = yc_on + (size_t)b * HH * WW;
    const float x = px, y = py;
    int ix = clampi((int)floorf(x * 127.0f), 0, 126);
    int iy = clampi((int)floorf(y * 127.0f), 0, 126);
    const float x0 = (float)ix * (1.0f / 127.0f);
    const float x1 = (float)(ix + 1) * (1.0f / 127.0f);
    const float y0 = (float)iy * (1.0f / 127.0f);
    const float y1 = (float)(iy + 1) * (1.0f / 127.0f);
    const float wx = (x - x0) / (x1 - x0);
    const float wy = (y - y0) / (y1 - y0);
    const float v00 = vals[ix * WW + iy];
    const float v01 = vals[ix * WW + iy + 1];
    const float v10 = vals[(ix + 1) * WW + iy];
    const float v11 = vals[(ix + 1) * WW + iy + 1];
    float vi = (1.f - wx) * (1.f - wy) * v00
             + (1.f - wx) * wy         * v01
             + wx         * (1.f - wy) * v10
             + wx         * wy         * v11;
    const bool oob = (x < 0.f) || (x > 1.f) || (y < 0.f) || (y > 1.f);
    const float yon = oob ? means[b] : vi;
    const float l   = logit_p[0];
    const float mix = 1.f / (1.f + expf(-l));
    return mix * bv + (1.f - mix) * yon;
}

// ---------------------------------------------------------------------------
// Kernel 3: one WAVE per query. Lanes scan cell-rows in parallel (independent
// row gathers -> one latency round-trip), then 6-step shfl_xor lexicographic
// (d2, idx) argmin. Ring expansion re-scans the full square — idempotent
// under the order-independent lexicographic min (same semantics validated
// absmax 0.0 in R3).
// ---------------------------------------------------------------------------
__global__ __launch_bounds__(256)
void query_kernel(const int* __restrict__ starts,
                  const float4* __restrict__ cellData,
                  const float* __restrict__ yc_on,    // (B,H,W)
                  const float* __restrict__ xt,       // (B,M,2)
                  const float* __restrict__ means,    // (B)
                  const float* __restrict__ logit_p,  // (1)
                  float* __restrict__ out)            // (B,M)
{
    const int lane = threadIdx.x & 63;
    int pid = blockIdx.x * 4 + (threadIdx.x >> 6);       // wave id == query id
    pid = __builtin_amdgcn_readfirstlane(pid);           // force SGPR/uniform
    const int b = pid >> 12;                             // / MM
    const int m = pid & (MM - 1);

    const float2 pt = ((const float2*)xt)[pid];          // uniform -> s_load
    const float px = pt.x, py = pt.y;

    const int cx = clampi((int)(px * (float)G), 0, G - 1);
    const int cy = clampi((int)(py * (float)G), 0, G - 1);

    const int*    __restrict__ st = starts + b * (GG + 1);
    const float4* __restrict__ cd = cellData + (size_t)b * NN;

    float bd = FLT_MAX;
    float bv = 0.f;
    int   bi = 0x7fffffff;

    for (int r = 1; r <= G; ++r) {
        const int gx0 = clampi(cx - r, 0, G - 1);
        const int gx1 = clampi(cx + r, 0, G - 1);
        const int gy0 = clampi(cy - r, 0, G - 1);
        const int gy1 = clampi(cy + r, 0, G - 1);

        for (int gx = gx0; gx <= gx1; ++gx) {
            const int lo = st[gx * G + gy0];             // wave-uniform
            const int hi = st[gx * G + gy1 + 1];
            for (int j = lo + lane; j < hi; j += 64) {   // parallel row gather
                const float4 c = cd[j];
                const float dx = px - c.x;
                const float dy = py - c.y;
                const float d2 = fmaf(dx, dx, dy * dy);
                const int   ci = __float_as_int(c.w);
                if (d2 < bd || (d2 == bd && ci < bi)) { bd = d2; bv = c.z; bi = ci; }
            }
        }

        // wave-wide lexicographic argmin; all lanes converge to the minimum
        for (int off = 1; off < 64; off <<= 1) {
            const float od = __shfl_xor(bd, off, 64);
            const float ov = __shfl_xor(bv, off, 64);
            const int   oi = __shfl_xor(bi, off, 64);
            if (od < bd || (od == bd && oi < bi)) { bd = od; bv = ov; bi = oi; }
        }

        // after square r, all unseen candidates are >= r*CELL away
        const float rr = (float)r * CELL;
        if (rr * rr > bd) break;
    }

    if (lane == 0)
        out[(size_t)b * MM + m] = epilogue(yc_on, means, logit_p, b, px, py, bv);
}

// ---------------------------------------------------------------------------
// Fallback: R1 brute-force NN (validated absmax 0.0) — only if ws too small.
// ---------------------------------------------------------------------------
#define WAVES 8
#define PTS 64
#define SLICE (NN / WAVES)

__global__ __launch_bounds__(WAVES * 64)
void nn_kernel(const float* __restrict__ xc_off,
               const float* __restrict__ yc_off,
               const float* __restrict__ yc_on,
               const float* __restrict__ xt,
               const float* __restrict__ means,
               const float* __restrict__ logit_p,
               float* __restrict__ out)
{
    const int blocksPerBatch = MM / PTS;
    const int b     = blockIdx.x / blocksPerBatch;
    const int pbase = (blockIdx.x % blocksPerBatch) * PTS;
    const int wave  = threadIdx.x >> 6;
    const int lane  = threadIdx.x & 63;
    const int m     = pbase + lane;

    const float2 pt = ((const float2*)xt)[b * MM + m];
    const float px = pt.x, py = pt.y;

    const float2* __restrict__ cxy = ((const float2*)xc_off) + (size_t)b * NN;
    const float*  __restrict__ cv  = yc_off + (size_t)b * NN;

    float best = 3.4e38f, bestv = 0.f;
    const int j0 = wave * SLICE;
    for (int t = 0; t < SLICE; t += 8) {
#pragma unroll
        for (int u = 0; u < 8; ++u) {
            const int j = j0 + t + u;
            const float2 c = cxy[j];
            const float  v = cv[j];
            const float dx = px - c.x;
            const float dy = py - c.y;
            const float d2 = fmaf(dx, dx, dy * dy);
            const bool lt = d2 < best;
            best  = lt ? d2 : best;
            bestv = lt ? v  : bestv;
        }
    }

    __shared__ float sd2[WAVES][PTS];
    __shared__ float sv [WAVES][PTS];
    sd2[wave][lane] = best;
    sv [wave][lane] = bestv;
    __syncthreads();

    if (threadIdx.x < PTS) {
        float bd = sd2[0][lane];
        float bv = sv [0][lane];
#pragma unroll
        for (int wv = 1; wv < WAVES; ++wv) {
            if (sd2[wv][lane] < bd) { bd = sd2[wv][lane]; bv = sv[wv][lane]; }
        }
        out[(size_t)b * MM + m] = epilogue(yc_on, means, logit_p, b, px, py, bv);
    }
}

// ---------------------------------------------------------------------------
extern "C" void kernel_launch(void* const* d_in, const int* in_sizes, int n_in,
                              void* d_out, int out_size, void* d_ws, size_t ws_size,
                              hipStream_t stream) {
    const float* xc_off = (const float*)d_in[0];   // (B,N,2)
    const float* yc_off = (const float*)d_in[1];   // (B,N)
    // d_in[2] = xc_on_grid (regular linspace grid, not needed)
    const float* yc_on  = (const float*)d_in[3];   // (B,H,W)
    const float* xt     = (const float*)d_in[4];   // (B,M,2)
    const float* logit  = (const float*)d_in[5];   // scalar
    float* out = (float*)d_out;

    float* means = (float*)d_ws;

    if (ws_size >= WS_NEEDED) {
        int*    counts   = (int*)((char*)d_ws + WS_COUNTS_OFF);    // -> cursors
        int*    starts   = (int*)((char*)d_ws + WS_STARTS_OFF);
        float4* cellData = (float4*)((char*)d_ws + WS_CELLS_OFF);

        mean_zero_kernel<<<BB, 256, 0, stream>>>(yc_on, means, counts);
        count_kernel<<<128, 256, 0, stream>>>(xc_off, counts);
        scan_kernel<<<BB, 1024, 0, stream>>>(counts, starts);
        scatter_kernel<<<128, 256, 0, stream>>>(xc_off, yc_off, counts, cellData);
        query_kernel<<<(BB * MM) / 4, 256, 0, stream>>>(
            starts, cellData, yc_on, xt, means, logit, out);
    } else {
        mean_zero_kernel<<<BB, 256, 0, stream>>>(yc_on, means, nullptr);
        nn_kernel<<<BB * (MM / PTS), WAVES * 64, 0, stream>>>(
            xc_off, yc_off, yc_on, xt, means, logit, out);
    }
}

// Round 5
// 105.857 us; speedup vs baseline: 1.6807x; 1.0717x over previous
//
#include <hip/hip_runtime.h>
#include <math.h>
#include <float.h>

#define BB 8
#define NN 8192
#define MM 4096
#define HH 128
#define WW 128

#define G    32
#define GG   (G * G)
#define CELL (1.0f / G)

// ws layout (16B-aligned sections):
//   [0, 32)              means (8 floats)
//   [256, 33024)         counts->cursors (B x GG ints, reused in-place)
//   [33024, 65824)       starts (B x (GG+1) ints)
//   [65824, +1MiB)       cellData (B x N float4: x, y, val, idx-bits)
#define WS_COUNTS_OFF 256
#define WS_STARTS_OFF 33024
#define WS_CELLS_OFF  65824
#define WS_NEEDED     (WS_CELLS_OFF + (size_t)BB * NN * 16)

__device__ __forceinline__ int clampi(int v, int lo, int hi) {
    return v < lo ? lo : (v > hi ? hi : v);
}

// ---------------------------------------------------------------------------
// Kernel A: count candidates per cell (one point per thread, global atomics).
// ---------------------------------------------------------------------------
__global__ __launch_bounds__(256)
void count_kernel(const float* __restrict__ xc_off,   // (B,N,2)
                  int* __restrict__ counts) {         // (B,GG)
    const int idx = blockIdx.x * blockDim.x + threadIdx.x;   // 0 .. B*N-1
    const int b = idx >> 13;                                 // / NN
    const float2 c = ((const float2*)xc_off)[idx];
    const int gx = clampi((int)(c.x * (float)G), 0, G - 1);
    const int gy = clampi((int)(c.y * (float)G), 0, G - 1);
    atomicAdd(&counts[b * GG + gx * G + gy], 1);
}

// ---------------------------------------------------------------------------
// Kernel B: per-batch exclusive scan of counts -> starts (+cursor reset),
// fused with the per-batch mean of yc_on. Mean keeps the EXACT 256-thread x
// 64-term summation order validated bit-exact (absmax 0.0) in R1/R3/R4.
// Scan code validated in R3/R4.
// ---------------------------------------------------------------------------
__global__ __launch_bounds__(1024)
void scan_mean_kernel(int* __restrict__ counts,            // (B,GG) -> cursors
                      int* __restrict__ starts,            // (B,GG+1)
                      const float* __restrict__ yc_on,     // (B,H,W)
                      float* __restrict__ means) {         // (B)
    const int b = blockIdx.x, tid = threadIdx.x;
    __shared__ int   wsum[16];
    __shared__ float partial[4];

    // ---- scan phase (all 1024 threads) ----
    const int orig = counts[b * GG + tid];
    int x = orig;
    const int lane = tid & 63, wid = tid >> 6;
    for (int off = 1; off < 64; off <<= 1) {
        int y = __shfl_up(x, off, 64);
        if (lane >= off) x += y;
    }
    if (lane == 63) wsum[wid] = x;
    __syncthreads();
    if (tid < 16) {
        int w = wsum[tid];
        for (int off = 1; off < 16; off <<= 1) {
            int y = __shfl_up(w, off, 16);
            if (tid >= off) w += y;
        }
        wsum[tid] = w;
    }
    __syncthreads();
    const int incl = x + (wid ? wsum[wid - 1] : 0);
    const int excl = incl - orig;
    starts[b * (GG + 1) + tid] = excl;
    if (tid == GG - 1) starts[b * (GG + 1) + GG] = incl;   // == N
    counts[b * GG + tid] = excl;   // cursor for scatter

    // ---- mean phase (first 256 threads; same arithmetic order as before) ----
    float s = 0.f;
    if (tid < 256) {
        const float* p = yc_on + b * (HH * WW);
        for (int i = tid; i < HH * WW; i += 256) s += p[i];
        for (int off = 32; off > 0; off >>= 1) s += __shfl_down(s, off, 64);
    }
    if (tid < 256 && (tid & 63) == 0) partial[tid >> 6] = s;
    __syncthreads();
    if (tid == 0) {
        float t = 0.f;
        for (int i = 0; i < 4; ++i) t += partial[i];
        means[b] = t * (1.0f / (HH * WW));
    }
}

// ---------------------------------------------------------------------------
// Kernel C: scatter candidates into cell order (atomic cursors). Bin-internal
// order nondeterministic; harmless — query uses order-independent
// lexicographic (d2, idx) min.
// ---------------------------------------------------------------------------
__global__ __launch_bounds__(256)
void scatter_kernel(const float* __restrict__ xc_off,  // (B,N,2)
                    const float* __restrict__ yc_off,  // (B,N)
                    int* __restrict__ cursors,         // (B,GG)
                    float4* __restrict__ cellData) {   // (B,N)
    const int idx = blockIdx.x * blockDim.x + threadIdx.x;
    const int b = idx >> 13;
    const int n = idx & (NN - 1);       // within-batch index
    const float2 c = ((const float2*)xc_off)[idx];
    const float v = yc_off[idx];
    const int gx = clampi((int)(c.x * (float)G), 0, G - 1);
    const int gy = clampi((int)(c.y * (float)G), 0, G - 1);
    const int pos = atomicAdd(&cursors[b * GG + gx * G + gy], 1);
    cellData[(size_t)b * NN + pos] = make_float4(c.x, c.y, v, __int_as_float(n));
}

// ---------------------------------------------------------------------------
// Bilinear + mix epilogue (validated bit-exact in R1/R3/R4).
// ---------------------------------------------------------------------------
__device__ __forceinline__ float epilogue(const float* __restrict__ yc_on,
                                          const float* __restrict__ means,
                                          const float* __restrict__ logit_p,
                                          int b, float px, float py, float bv) {
    const float* __restrict__ vals = yc_on + (size_t)b * HH * WW;
    const float x = px, y = py;
    int ix = clampi((int)floorf(x * 127.0f), 0, 126);
    int iy = clampi((int)floorf(y * 127.0f), 0, 126);
    const float x0 = (float)ix * (1.0f / 127.0f);
    const float x1 = (float)(ix + 1) * (1.0f / 127.0f);
    const float y0 = (float)iy * (1.0f / 127.0f);
    const float y1 = (float)(iy + 1) * (1.0f / 127.0f);
    const float wx = (x - x0) / (x1 - x0);
    const float wy = (y - y0) / (y1 - y0);
    const float v00 = vals[ix * WW + iy];
    const float v01 = vals[ix * WW + iy + 1];
    const float v10 = vals[(ix + 1) * WW + iy];
    const float v11 = vals[(ix + 1) * WW + iy + 1];
    float vi = (1.f - wx) * (1.f - wy) * v00
             + (1.f - wx) * wy         * v01
             + wx         * (1.f - wy) * v10
             + wx         * wy         * v11;
    const bool oob = (x < 0.f) || (x > 1.f) || (y < 0.f) || (y > 1.f);
    const float yon = oob ? means[b] : vi;
    const float l   = logit_p[0];
    const float mix = 1.f / (1.f + expf(-l));
    return mix * bv + (1.f - mix) * yon;
}

// ---------------------------------------------------------------------------
// Kernel D: NN query — 2 queries per wave (independent 32-lane halves).
// Lanes of a half scan cell-rows in parallel, then a 5-step xor-shuffle
// lexicographic (d2, idx) argmin (xor offsets < 32 stay within each half).
// Ring re-scan is idempotent under the order-independent lexicographic min.
// Same NN semantics validated absmax 0.0 in R3/R4.
// ---------------------------------------------------------------------------
__global__ __launch_bounds__(256)
void query_kernel(const int* __restrict__ starts,
                  const float4* __restrict__ cellData,
                  const float* __restrict__ yc_on,    // (B,H,W)
                  const float* __restrict__ xt,       // (B,M,2)
                  const float* __restrict__ means,    // (B)
                  const float* __restrict__ logit_p,  // (1)
                  float* __restrict__ out)            // (B,M)
{
    const int lane32 = threadIdx.x & 31;
    const int pid = blockIdx.x * 8 + (threadIdx.x >> 5);   // half-wave id
    const int b = pid >> 12;                               // / MM
    const int m = pid & (MM - 1);

    const float2 pt = ((const float2*)xt)[pid];
    const float px = pt.x, py = pt.y;

    const int cx = clampi((int)(px * (float)G), 0, G - 1);
    const int cy = clampi((int)(py * (float)G), 0, G - 1);

    const int*    __restrict__ st = starts + b * (GG + 1);
    const float4* __restrict__ cd = cellData + (size_t)b * NN;

    float bd = FLT_MAX;
    float bv = 0.f;
    int   bi = 0x7fffffff;

    for (int r = 1; r <= G; ++r) {
        const int gx0 = clampi(cx - r, 0, G - 1);
        const int gx1 = clampi(cx + r, 0, G - 1);
        const int gy0 = clampi(cy - r, 0, G - 1);
        const int gy1 = clampi(cy + r, 0, G - 1);

        for (int gx = gx0; gx <= gx1; ++gx) {
            const int lo = st[gx * G + gy0];
            const int hi = st[gx * G + gy1 + 1];
            for (int j = lo + lane32; j < hi; j += 32) {  // parallel row gather
                const float4 c = cd[j];
                const float dx = px - c.x;
                const float dy = py - c.y;
                const float d2 = fmaf(dx, dx, dy * dy);
                const int   ci = __float_as_int(c.w);
                if (d2 < bd || (d2 == bd && ci < bi)) { bd = d2; bv = c.z; bi = ci; }
            }
        }

        // half-wave lexicographic argmin (offsets 1..16 stay in each half)
        for (int off = 1; off < 32; off <<= 1) {
            const float od = __shfl_xor(bd, off, 64);
            const float ov = __shfl_xor(bv, off, 64);
            const int   oi = __shfl_xor(bi, off, 64);
            if (od < bd || (od == bd && oi < bi)) { bd = od; bv = ov; bi = oi; }
        }

        // after square r, all unseen candidates are >= r*CELL away
        const float rr = (float)r * CELL;
        if (rr * rr > bd) break;
    }

    if (lane32 == 0)
        out[(size_t)b * MM + m] = epilogue(yc_on, means, logit_p, b, px, py, bv);
}

// ---------------------------------------------------------------------------
// Fallback: R1 brute-force NN (validated absmax 0.0) — only if ws too small.
// ---------------------------------------------------------------------------
#define WAVES 8
#define PTS 64
#define SLICE (NN / WAVES)

__global__ void mean_kernel(const float* __restrict__ yc_on,
                            float* __restrict__ means) {
    int b = blockIdx.x;
    const float* p = yc_on + b * (HH * WW);
    float s = 0.f;
    for (int i = threadIdx.x; i < HH * WW; i += blockDim.x) s += p[i];
    for (int off = 32; off > 0; off >>= 1) s += __shfl_down(s, off, 64);
    __shared__ float partial[4];
    int wave = threadIdx.x >> 6;
    if ((threadIdx.x & 63) == 0) partial[wave] = s;
    __syncthreads();
    if (threadIdx.x == 0) {
        float t = 0.f;
        int nw = blockDim.x >> 6;
        for (int i = 0; i < nw; ++i) t += partial[i];
        means[b] = t * (1.0f / (HH * WW));
    }
}

__global__ __launch_bounds__(WAVES * 64)
void nn_kernel(const float* __restrict__ xc_off,
               const float* __restrict__ yc_off,
               const float* __restrict__ yc_on,
               const float* __restrict__ xt,
               const float* __restrict__ means,
               const float* __restrict__ logit_p,
               float* __restrict__ out)
{
    const int blocksPerBatch = MM / PTS;
    const int b     = blockIdx.x / blocksPerBatch;
    const int pbase = (blockIdx.x % blocksPerBatch) * PTS;
    const int wave  = threadIdx.x >> 6;
    const int lane  = threadIdx.x & 63;
    const int m     = pbase + lane;

    const float2 pt = ((const float2*)xt)[b * MM + m];
    const float px = pt.x, py = pt.y;

    const float2* __restrict__ cxy = ((const float2*)xc_off) + (size_t)b * NN;
    const float*  __restrict__ cv  = yc_off + (size_t)b * NN;

    float best = 3.4e38f, bestv = 0.f;
    const int j0 = wave * SLICE;
    for (int t = 0; t < SLICE; t += 8) {
#pragma unroll
        for (int u = 0; u < 8; ++u) {
            const int j = j0 + t + u;
            const float2 c = cxy[j];
            const float  v = cv[j];
            const float dx = px - c.x;
            const float dy = py - c.y;
            const float d2 = fmaf(dx, dx, dy * dy);
            const bool lt = d2 < best;
            best  = lt ? d2 : best;
            bestv = lt ? v  : bestv;
        }
    }

    __shared__ float sd2[WAVES][PTS];
    __shared__ float sv [WAVES][PTS];
    sd2[wave][lane] = best;
    sv [wave][lane] = bestv;
    __syncthreads();

    if (threadIdx.x < PTS) {
        float bd = sd2[0][lane];
        float bv = sv [0][lane];
#pragma unroll
        for (int wv = 1; wv < WAVES; ++wv) {
            if (sd2[wv][lane] < bd) { bd = sd2[wv][lane]; bv = sv[wv][lane]; }
        }
        out[(size_t)b * MM + m] = epilogue(yc_on, means, logit_p, b, px, py, bv);
    }
}

// ---------------------------------------------------------------------------
extern "C" void kernel_launch(void* const* d_in, const int* in_sizes, int n_in,
                              void* d_out, int out_size, void* d_ws, size_t ws_size,
                              hipStream_t stream) {
    const float* xc_off = (const float*)d_in[0];   // (B,N,2)
    const float* yc_off = (const float*)d_in[1];   // (B,N)
    // d_in[2] = xc_on_grid (regular linspace grid, not needed)
    const float* yc_on  = (const float*)d_in[3];   // (B,H,W)
    const float* xt     = (const float*)d_in[4];   // (B,M,2)
    const float* logit  = (const float*)d_in[5];   // scalar
    float* out = (float*)d_out;

    float* means = (float*)d_ws;

    if (ws_size >= WS_NEEDED) {
        int*    counts   = (int*)((char*)d_ws + WS_COUNTS_OFF);    // -> cursors
        int*    starts   = (int*)((char*)d_ws + WS_STARTS_OFF);
        float4* cellData = (float4*)((char*)d_ws + WS_CELLS_OFF);

        hipMemsetAsync(counts, 0, (size_t)BB * GG * sizeof(int), stream);
        count_kernel<<<(BB * NN) / 256, 256, 0, stream>>>(xc_off, counts);
        scan_mean_kernel<<<BB, 1024, 0, stream>>>(counts, starts, yc_on, means);
        scatter_kernel<<<(BB * NN) / 256, 256, 0, stream>>>(
            xc_off, yc_off, counts, cellData);
        query_kernel<<<(BB * MM) / 8, 256, 0, stream>>>(
            starts, cellData, yc_on, xt, means, logit, out);
    } else {
        mean_kernel<<<BB, 256, 0, stream>>>(yc_on, means);
        nn_kernel<<<BB * (MM / PTS), WAVES * 64, 0, stream>>>(
            xc_off, yc_off, yc_on, xt, means, logit, out);
    }
}

// Round 6
// 104.949 us; speedup vs baseline: 1.6952x; 1.0086x over previous
//
#include <hip/hip_runtime.h>
#include <math.h>
#include <float.h>

#define BB 8
#define NN 8192
#define MM 4096
#define HH 128
#define WW 128

#define G    32
#define GG   (G * G)
#define CELL (1.0f / G)

// ws layout (16B-aligned sections):
//   [0, 32)              means (8 floats)
//   [256, 33056)         starts (B x (GG+1) ints)
//   [33056, +1MiB)       cellData (B x N float4: x, y, val, idx-bits)
#define WS_STARTS_OFF 256
#define WS_CELLS_OFF  33056
#define WS_NEEDED     (WS_CELLS_OFF + (size_t)BB * NN * 16)

__device__ __forceinline__ int clampi(int v, int lo, int hi) {
    return v < lo ? lo : (v > hi ? hi : v);
}

// ---------------------------------------------------------------------------
// Kernel 1: fused binning (count -> LDS scan -> scatter; validated absmax 0.0
// in R3) + per-batch mean of yc_on (exact 256-thread x 64-term summation
// order validated bit-exact in R1/R3/R4/R5). One block per batch.
// ---------------------------------------------------------------------------
__global__ __launch_bounds__(1024)
void bin_mean_kernel(const float* __restrict__ xc_off,   // (B,N,2)
                     const float* __restrict__ yc_off,   // (B,N)
                     const float* __restrict__ yc_on,    // (B,H,W)
                     int* __restrict__ starts,           // (B, GG+1)
                     float4* __restrict__ cellData,      // (B, N)
                     float* __restrict__ means)          // (B)
{
    const int b   = blockIdx.x;
    const int tid = threadIdx.x;
    __shared__ int   cnt[GG];
    __shared__ int   wsum[16];
    __shared__ float partial[4];
    cnt[tid] = 0;
    __syncthreads();

    const float2* __restrict__ cxy = ((const float2*)xc_off) + (size_t)b * NN;
    float2 pts[NN / 1024];
    int    cells[NN / 1024];
#pragma unroll
    for (int k = 0; k < NN / 1024; ++k) {
        float2 c = cxy[tid + k * 1024];
        int gx = clampi((int)(c.x * (float)G), 0, G - 1);
        int gy = clampi((int)(c.y * (float)G), 0, G - 1);
        pts[k]   = c;
        cells[k] = gx * G + gy;
        atomicAdd(&cnt[cells[k]], 1);
    }
    __syncthreads();

    // exclusive scan over the 1024 cell counts (validated R3)
    const int orig = cnt[tid];
    int x = orig;
    const int lane = tid & 63, wid = tid >> 6;
    for (int off = 1; off < 64; off <<= 1) {
        int y = __shfl_up(x, off, 64);
        if (lane >= off) x += y;
    }
    if (lane == 63) wsum[wid] = x;
    __syncthreads();
    if (tid < 16) {
        int w = wsum[tid];
        for (int off = 1; off < 16; off <<= 1) {
            int y = __shfl_up(w, off, 16);
            if (tid >= off) w += y;
        }
        wsum[tid] = w;
    }
    __syncthreads();
    const int incl = x + (wid ? wsum[wid - 1] : 0);
    const int excl = incl - orig;
    starts[b * (GG + 1) + tid] = excl;
    if (tid == GG - 1) starts[b * (GG + 1) + GG] = incl;   // == N
    __syncthreads();
    cnt[tid] = excl;   // running cursors for scatter
    __syncthreads();

    const float* __restrict__ cv = yc_off + (size_t)b * NN;
#pragma unroll
    for (int k = 0; k < NN / 1024; ++k) {
        const int i = tid + k * 1024;
        const float v = cv[i];
        const int pos = atomicAdd(&cnt[cells[k]], 1);
        cellData[(size_t)b * NN + pos] =
            make_float4(pts[k].x, pts[k].y, v, __int_as_float(i));
    }

    // ---- mean phase (first 256 threads; bit-exact summation order) ----
    float s = 0.f;
    if (tid < 256) {
        const float* p = yc_on + b * (HH * WW);
        for (int i = tid; i < HH * WW; i += 256) s += p[i];
        for (int off = 32; off > 0; off >>= 1) s += __shfl_down(s, off, 64);
    }
    if (tid < 256 && (tid & 63) == 0) partial[tid >> 6] = s;
    __syncthreads();
    if (tid == 0) {
        float t = 0.f;
        for (int i = 0; i < 4; ++i) t += partial[i];
        means[b] = t * (1.0f / (HH * WW));
    }
}

// ---------------------------------------------------------------------------
// Bilinear + mix epilogue (validated bit-exact in R1/R3/R4/R5).
// ---------------------------------------------------------------------------
__device__ __forceinline__ float epilogue(const float* __restrict__ yc_on,
                                          const float* __restrict__ means,
                                          const float* __restrict__ logit_p,
                                          int b, float px, float py, float bv) {
    const float* __restrict__ vals = yc_on + (size_t)b * HH * WW;
    const float x = px, y = py;
    int ix = clampi((int)floorf(x * 127.0f), 0, 126);
    int iy = clampi((int)floorf(y * 127.0f), 0, 126);
    const float x0 = (float)ix * (1.0f / 127.0f);
    const float x1 = (float)(ix + 1) * (1.0f / 127.0f);
    const float y0 = (float)iy * (1.0f / 127.0f);
    const float y1 = (float)(iy + 1) * (1.0f / 127.0f);
    const float wx = (x - x0) / (x1 - x0);
    const float wy = (y - y0) / (y1 - y0);
    const float v00 = vals[ix * WW + iy];
    const float v01 = vals[ix * WW + iy + 1];
    const float v10 = vals[(ix + 1) * WW + iy];
    const float v11 = vals[(ix + 1) * WW + iy + 1];
    float vi = (1.f - wx) * (1.f - wy) * v00
             + (1.f - wx) * wy         * v01
             + wx         * (1.f - wy) * v10
             + wx         * wy         * v11;
    const bool oob = (x < 0.f) || (x > 1.f) || (y < 0.f) || (y > 1.f);
    const float yon = oob ? means[b] : vi;
    const float l   = logit_p[0];
    const float mix = 1.f / (1.f + expf(-l));
    return mix * bv + (1.f - mix) * yon;
}

// ---------------------------------------------------------------------------
// Kernel 2: NN query — 2 queries per wave (independent 32-lane halves),
// unchanged from R5 (validated absmax 0.0). Lanes of a half scan cell-rows
// in parallel, then a 5-step xor-shuffle lexicographic (d2, idx) argmin.
// Ring re-scan is idempotent under the order-independent lexicographic min.
// ---------------------------------------------------------------------------
__global__ __launch_bounds__(256)
void query_kernel(const int* __restrict__ starts,
                  const float4* __restrict__ cellData,
                  const float* __restrict__ yc_on,    // (B,H,W)
                  const float* __restrict__ xt,       // (B,M,2)
                  const float* __restrict__ means,    // (B)
                  const float* __restrict__ logit_p,  // (1)
                  float* __restrict__ out)            // (B,M)
{
    const int lane32 = threadIdx.x & 31;
    const int pid = blockIdx.x * 8 + (threadIdx.x >> 5);   // half-wave id
    const int b = pid >> 12;                               // / MM
    const int m = pid & (MM - 1);

    const float2 pt = ((const float2*)xt)[pid];
    const float px = pt.x, py = pt.y;

    const int cx = clampi((int)(px * (float)G), 0, G - 1);
    const int cy = clampi((int)(py * (float)G), 0, G - 1);

    const int*    __restrict__ st = starts + b * (GG + 1);
    const float4* __restrict__ cd = cellData + (size_t)b * NN;

    float bd = FLT_MAX;
    float bv = 0.f;
    int   bi = 0x7fffffff;

    for (int r = 1; r <= G; ++r) {
        const int gx0 = clampi(cx - r, 0, G - 1);
        const int gx1 = clampi(cx + r, 0, G - 1);
        const int gy0 = clampi(cy - r, 0, G - 1);
        const int gy1 = clampi(cy + r, 0, G - 1);

        for (int gx = gx0; gx <= gx1; ++gx) {
            const int lo = st[gx * G + gy0];
            const int hi = st[gx * G + gy1 + 1];
            for (int j = lo + lane32; j < hi; j += 32) {  // parallel row gather
                const float4 c = cd[j];
                const float dx = px - c.x;
                const float dy = py - c.y;
                const float d2 = fmaf(dx, dx, dy * dy);
                const int   ci = __float_as_int(c.w);
                if (d2 < bd || (d2 == bd && ci < bi)) { bd = d2; bv = c.z; bi = ci; }
            }
        }

        // half-wave lexicographic argmin (offsets 1..16 stay in each half)
        for (int off = 1; off < 32; off <<= 1) {
            const float od = __shfl_xor(bd, off, 64);
            const float ov = __shfl_xor(bv, off, 64);
            const int   oi = __shfl_xor(bi, off, 64);
            if (od < bd || (od == bd && oi < bi)) { bd = od; bv = ov; bi = oi; }
        }

        // after square r, all unseen candidates are >= r*CELL away
        const float rr = (float)r * CELL;
        if (rr * rr > bd) break;
    }

    if (lane32 == 0)
        out[(size_t)b * MM + m] = epilogue(yc_on, means, logit_p, b, px, py, bv);
}

// ---------------------------------------------------------------------------
// Fallback: R1 brute-force NN (validated absmax 0.0) — only if ws too small.
// ---------------------------------------------------------------------------
#define WAVES 8
#define PTS 64
#define SLICE (NN / WAVES)

__global__ void mean_kernel(const float* __restrict__ yc_on,
                            float* __restrict__ means) {
    int b = blockIdx.x;
    const float* p = yc_on + b * (HH * WW);
    float s = 0.f;
    for (int i = threadIdx.x; i < HH * WW; i += blockDim.x) s += p[i];
    for (int off = 32; off > 0; off >>= 1) s += __shfl_down(s, off, 64);
    __shared__ float partial[4];
    int wave = threadIdx.x >> 6;
    if ((threadIdx.x & 63) == 0) partial[wave] = s;
    __syncthreads();
    if (threadIdx.x == 0) {
        float t = 0.f;
        int nw = blockDim.x >> 6;
        for (int i = 0; i < nw; ++i) t += partial[i];
        means[b] = t * (1.0f / (HH * WW));
    }
}

__global__ __launch_bounds__(WAVES * 64)
void nn_kernel(const float* __restrict__ xc_off,
               const float* __restrict__ yc_off,
               const float* __restrict__ yc_on,
               const float* __restrict__ xt,
               const float* __restrict__ means,
               const float* __restrict__ logit_p,
               float* __restrict__ out)
{
    const int blocksPerBatch = MM / PTS;
    const int b     = blockIdx.x / blocksPerBatch;
    const int pbase = (blockIdx.x % blocksPerBatch) * PTS;
    const int wave  = threadIdx.x >> 6;
    const int lane  = threadIdx.x & 63;
    const int m     = pbase + lane;

    const float2 pt = ((const float2*)xt)[b * MM + m];
    const float px = pt.x, py = pt.y;

    const float2* __restrict__ cxy = ((const float2*)xc_off) + (size_t)b * NN;
    const float*  __restrict__ cv  = yc_off + (size_t)b * NN;

    float best = 3.4e38f, bestv = 0.f;
    const int j0 = wave * SLICE;
    for (int t = 0; t < SLICE; t += 8) {
#pragma unroll
        for (int u = 0; u < 8; ++u) {
            const int j = j0 + t + u;
            const float2 c = cxy[j];
            const float  v = cv[j];
            const float dx = px - c.x;
            const float dy = py - c.y;
            const float d2 = fmaf(dx, dx, dy * dy);
            const bool lt = d2 < best;
            best  = lt ? d2 : best;
            bestv = lt ? v  : bestv;
        }
    }

    __shared__ float sd2[WAVES][PTS];
    __shared__ float sv [WAVES][PTS];
    sd2[wave][lane] = best;
    sv [wave][lane] = bestv;
    __syncthreads();

    if (threadIdx.x < PTS) {
        float bd = sd2[0][lane];
        float bv = sv [0][lane];
#pragma unroll
        for (int wv = 1; wv < WAVES; ++wv) {
            if (sd2[wv][lane] < bd) { bd = sd2[wv][lane]; bv = sv[wv][lane]; }
        }
        out[(size_t)b * MM + m] = epilogue(yc_on, means, logit_p, b, px, py, bv);
    }
}

// ---------------------------------------------------------------------------
extern "C" void kernel_launch(void* const* d_in, const int* in_sizes, int n_in,
                              void* d_out, int out_size, void* d_ws, size_t ws_size,
                              hipStream_t stream) {
    const float* xc_off = (const float*)d_in[0];   // (B,N,2)
    const float* yc_off = (const float*)d_in[1];   // (B,N)
    // d_in[2] = xc_on_grid (regular linspace grid, not needed)
    const float* yc_on  = (const float*)d_in[3];   // (B,H,W)
    const float* xt     = (const float*)d_in[4];   // (B,M,2)
    const float* logit  = (const float*)d_in[5];   // scalar
    float* out = (float*)d_out;

    float* means = (float*)d_ws;

    if (ws_size >= WS_NEEDED) {
        int*    starts   = (int*)((char*)d_ws + WS_STARTS_OFF);
        float4* cellData = (float4*)((char*)d_ws + WS_CELLS_OFF);

        bin_mean_kernel<<<BB, 1024, 0, stream>>>(
            xc_off, yc_off, yc_on, starts, cellData, means);
        query_kernel<<<(BB * MM) / 8, 256, 0, stream>>>(
            starts, cellData, yc_on, xt, means, logit, out);
    } else {
        mean_kernel<<<BB, 256, 0, stream>>>(yc_on, means);
        nn_kernel<<<BB * (MM / PTS), WAVES * 64, 0, stream>>>(
            xc_off, yc_off, yc_on, xt, means, logit, out);
    }
}